// Round 6
// baseline (303.521 us; speedup 1.0000x reference)
//
#include <hip/hip_runtime.h>
#include <hip/hip_bf16.h>

#define IN_DIM  64
#define HID     128
#define OUT_DIM 32

typedef short    v8s __attribute__((ext_vector_type(8)));
typedef float    v4f __attribute__((ext_vector_type(4)));
typedef unsigned v4u __attribute__((ext_vector_type(4)));

__device__ __forceinline__ float swishf(float v) {
    // v * sigmoid(v) with native v_exp / v_rcp
    return __fdividef(v, 1.0f + __expf(-v));
}
__device__ __forceinline__ unsigned pk2(float a, float b) {
    __hip_bfloat162 p = __float22bfloat162_rn(make_float2(a, b));
    return *(unsigned*)&p;
}

// Channel-permuted weight staging: tile T, row R holds physical channel
//   ch(T,R) = 32*(T>>1) + 8*(R>>2) + 4*(T&1) + (R&3)
// so each layer's MFMA C-output registers ARE the next layer's B-operand
// fragments (register-local handoff, zero main-loop barriers/slab).
//
// R5 -> R6: the body compiles to 64 VGPRs, so 8 waves/SIMD is legal; the
// only blocker was LDS = 82KB (weights 80KB + bias 2KB). Biases/head move
// to per-iter GLOBAL loads (L1/L2-resident, ~2KB/subnet) addressed through
// the same opaque-z voffset so LICM cannot hoist them into registers (the
// R4 spill mode). LDS = exactly 81920B -> 2 x 1024-thread blocks per CU.
__global__ __launch_bounds__(1024, 2)
void subnet_mlp(const float* __restrict__ x,  const float* __restrict__ W1,
                const float* __restrict__ b1, const float* __restrict__ Wh,
                const float* __restrict__ bh, const float* __restrict__ Wo,
                const float* __restrict__ bo, float* __restrict__ out,
                int n_iters)
{
    // swizzled: row R, 16B-slot kg stored at slot kg ^ (R&7)
    __shared__ __align__(16) short sW1[8 * 16 * 64];       // 16 KB, 8 tiles
    __shared__ __align__(16) short sWh[2 * 8 * 16 * 128];  // 64 KB, 2 layers
    // total 81920 B exactly -> two 1024-thread blocks co-resident per CU

    const int tid   = threadIdx.x;
    const int o     = blockIdx.x >> 4;    // subnet
    const int slice = blockIdx.x & 15;    // row-slice

    char* const cW1 = (char*)sW1;
    char* const cWh = (char*)sWh;

    // ---------------- one-time staging (bf16, permuted, swizzled) ----------------
    {   // W1: exactly 1024 tasks (T,R,kg)
        const int R = tid & 15, T = (tid >> 4) & 7, kg = tid >> 7;    // kg:0..7
        const int c = 32 * (T >> 1) + 8 * (R >> 2) + 4 * (T & 1) + (R & 3);
        const float* p = W1 + ((size_t)o * IN_DIM + kg * 8) * HID + c;
        union { v8s v; unsigned u[4]; } cv;
        #pragma unroll
        for (int j = 0; j < 4; ++j)
            cv.u[j] = pk2(p[(2 * j) * HID], p[(2 * j + 1) * HID]);
        *(v8s*)(cW1 + T * 2048 + R * 128 + ((kg * 16) ^ ((R & 7) << 4))) = cv.v;
    }
    #pragma unroll
    for (int r = 0; r < 4; ++r) {          // Wh: 4096 tasks (l,T,R,kg)
        const int t = tid + r * 1024;
        const int R = t & 15, T = (t >> 4) & 7, kg = (t >> 7) & 15, l = t >> 11;
        const int c = 32 * (T >> 1) + 8 * (R >> 2) + 4 * (T & 1) + (R & 3);
        const float* p = Wh + (((size_t)l * OUT_DIM + o) * HID + kg * 8) * HID + c;
        union { v8s v; unsigned u[4]; } cv;
        #pragma unroll
        for (int j = 0; j < 4; ++j)
            cv.u[j] = pk2(p[(2 * j) * HID], p[(2 * j + 1) * HID]);
        *(v8s*)(cWh + l * 32768 + T * 4096 + R * 256 + ((kg * 16) ^ ((R & 7) << 4))) = cv.v;
    }
    __syncthreads();   // the ONLY block-wide barrier

    const int lane = tid & 63;
    const int w    = tid >> 6;    // wave id 0..15: owns rows [w*16, w*16+16)
    const int n    = lane & 15;   // fragment row/col index
    const int q    = lane >> 4;   // quad
    const float bo_v = bo[o];

    // loop-invariant swizzled k-slot byte offsets
    int kW1[2], kWh[4];
    #pragma unroll
    for (int kc = 0; kc < 2; ++kc) kW1[kc] = ((4 * kc + q) ^ (n & 7)) << 4;
    #pragma unroll
    for (int kc = 0; kc < 4; ++kc) kWh[kc] = ((4 * kc + q) ^ (n & 7)) << 4;

    const int w1base = n * 128;
    const int whbase = n * 256;

    // uniform global bases (SGPR) for bias/head; per-lane part is 8q (+z voffset)
    const char* const gB1 = (const char*)(b1 + o * HID + 8 * q);
    const char* const gH0 = (const char*)(bh + o * HID + 8 * q);
    const char* const gH1 = (const char*)(bh + (OUT_DIM + o) * HID + 8 * q);
    const char* const gWo = (const char*)(Wo + o * HID + 8 * q);

    for (int it = 0; it < n_iters; ++it) {
        // opaque zero, re-laundered each iteration: defeats LICM on LDS and
        // bias loads (keeps them in-loop instead of hoisted->spilled)
        unsigned z = 0;
        asm volatile("" : "+v"(z));
        const char* const W1p = cW1 + w1base + z;   // + imm T*2048 + kW1[kc]
        const char* const Whp = cWh + whbase + z;   // + imm l*32768 + T*4096 + kWh[kc]
        const char* const B1p = gB1 + z;            // + imm 128*(T>>1)+16*(T&1)
        const char* const H0p = gH0 + z;
        const char* const H1p = gH1 + z;
        const char* const Wop = gWo + z;

        const int row = (slice * n_iters + it) * 256 + w * 16 + n;

        // ---- x fragments (B-operand, row-major, k-contiguous) ----
        v8s xb[2];
        #pragma unroll
        for (int kc = 0; kc < 2; ++kc) {
            const float* xp = x + (size_t)row * IN_DIM + kc * 32 + q * 8;
            float4 f0 = *(const float4*)xp;
            float4 f1 = *(const float4*)(xp + 4);
            union { v8s v; unsigned u[4]; } cv;
            cv.u[0] = pk2(f0.x, f0.y); cv.u[1] = pk2(f0.z, f0.w);
            cv.u[2] = pk2(f1.x, f1.y); cv.u[3] = pk2(f1.z, f1.w);
            xb[kc] = cv.v;
        }

        // ================= layer 1: C^T = W1^T @ X^T =================
        v4f acc[8];
        #pragma unroll
        for (int T = 0; T < 8; ++T)      // bias rides the accumulator init (L1-hit)
            acc[T] = *(const v4f*)(B1p + 128 * (T >> 1) + 16 * (T & 1));
        #pragma unroll
        for (int kc = 0; kc < 2; ++kc)
            #pragma unroll
            for (int T = 0; T < 8; ++T) {
                v8s a = *(const v8s*)(W1p + T * 2048 + kW1[kc]);
                acc[T] = __builtin_amdgcn_mfma_f32_16x16x32_bf16(a, xb[kc], acc[T], 0, 0, 0);
            }
        // packed H, filled directly in next-layer B-operand order (k-slot s:
        // T=2kc+hi gives s=4*hi+j) -- register-local layer handoff
        unsigned h[16];
        #pragma unroll
        for (int T = 0; T < 8; ++T) {
            h[(T >> 1) * 4 + 2 * (T & 1)]     = pk2(swishf(acc[T][0]), swishf(acc[T][1]));
            h[(T >> 1) * 4 + 2 * (T & 1) + 1] = pk2(swishf(acc[T][2]), swishf(acc[T][3]));
        }

        // ================= hidden layers =================
        #pragma unroll
        for (int l = 0; l < 2; ++l) {
            const char* const Bp = l ? H1p : H0p;
            #pragma unroll
            for (int T = 0; T < 8; ++T)
                acc[T] = *(const v4f*)(Bp + 128 * (T >> 1) + 16 * (T & 1));
            #pragma unroll
            for (int kc = 0; kc < 4; ++kc) {
                v4u tu = { h[kc * 4 + 0], h[kc * 4 + 1], h[kc * 4 + 2], h[kc * 4 + 3] };
                v8s hbv = __builtin_bit_cast(v8s, tu);
                #pragma unroll
                for (int T = 0; T < 8; ++T) {
                    v8s a = *(const v8s*)(Whp + l * 32768 + T * 4096 + kWh[kc]);
                    acc[T] = __builtin_amdgcn_mfma_f32_16x16x32_bf16(a, hbv, acc[T], 0, 0, 0);
                }
            }
            if (l == 0) {
                #pragma unroll
                for (int T = 0; T < 8; ++T) {
                    h[(T >> 1) * 4 + 2 * (T & 1)]     = pk2(swishf(acc[T][0]), swishf(acc[T][1]));
                    h[(T >> 1) * 4 + 2 * (T & 1) + 1] = pk2(swishf(acc[T][2]), swishf(acc[T][3]));
                }
            } else {
                // head fused into the epilogue (wo via L1-resident v4f loads)
                float p = 0.0f;
                #pragma unroll
                for (int T = 0; T < 8; ++T) {
                    v4f wo = *(const v4f*)(Wop + 128 * (T >> 1) + 16 * (T & 1));
                    p += swishf(acc[T][0]) * wo[0];
                    p += swishf(acc[T][1]) * wo[1];
                    p += swishf(acc[T][2]) * wo[2];
                    p += swishf(acc[T][3]) * wo[3];
                }
                p += __shfl_xor(p, 16);          // reduce across the 4 quads
                p += __shfl_xor(p, 32);
                if (lane < 16)
                    out[(size_t)row * OUT_DIM + o] = p + bo_v;
            }
        }
    }
}

extern "C" void kernel_launch(void* const* d_in, const int* in_sizes, int n_in,
                              void* d_out, int out_size, void* d_ws, size_t ws_size,
                              hipStream_t stream) {
    const float* x  = (const float*)d_in[0];
    const float* W1 = (const float*)d_in[1];
    const float* b1 = (const float*)d_in[2];
    const float* Wh = (const float*)d_in[3];
    const float* bh = (const float*)d_in[4];
    const float* Wo = (const float*)d_in[5];
    const float* bo = (const float*)d_in[6];
    float* out = (float*)d_out;

    const int N       = in_sizes[0] / IN_DIM;  // 32768
    const int n_iters = N / (16 * 256);        // 8: 16 slices x 256 rows/iter

    dim3 grid(OUT_DIM * 16);                   // 512 blocks: 32 subnets x 16 slices
    dim3 block(1024);                          // 16 waves; 80KB LDS -> 2 blocks/CU
    subnet_mlp<<<grid, block, 0, stream>>>(x, W1, b1, Wh, bh, Wo, bo, out, n_iters);
}

// Round 7
// 296.988 us; speedup vs baseline: 1.0220x; 1.0220x over previous
//
#include <hip/hip_runtime.h>
#include <hip/hip_bf16.h>

#define IN_DIM  64
#define HID     128
#define OUT_DIM 32

typedef short    v8s __attribute__((ext_vector_type(8)));
typedef float    v4f __attribute__((ext_vector_type(4)));
typedef unsigned v4u __attribute__((ext_vector_type(4)));

__device__ __forceinline__ float swishf(float v) {
    // v * sigmoid(v) with native v_exp / v_rcp
    return __fdividef(v, 1.0f + __expf(-v));
}
__device__ __forceinline__ unsigned pk2(float a, float b) {
    __hip_bfloat162 p = __float22bfloat162_rn(make_float2(a, b));
    return *(unsigned*)&p;
}

// Channel-permuted weight staging: tile T, row R holds physical channel
//   ch(T,R) = 32*(T>>1) + 8*(R>>2) + 4*(T&1) + (R&3)
// so each layer's MFMA C-output registers ARE the next layer's B-operand
// fragments (register-local handoff, zero main-loop barriers/slab).
//
// R6 -> R7: kernel is VALU/trans-issue-bound (VALUBusy 77%, ~210us of issue
// across all versions); occupancy is pinned at 4 waves/SIMD by 80KB LDS.
// With VGPR=56 vs the 128 cap, spend registers on ILP instead: each wave
// processes TWO row-tiles per iteration, fused at the MFMA level. Every
// weight A-fragment ds_read and every bias v4f load now feeds two
// independent MFMA chains, and each tile's layer-boundary swish drain
// overlaps the other tile's MFMAs.
__global__ __launch_bounds__(1024, 1)
void subnet_mlp(const float* __restrict__ x,  const float* __restrict__ W1,
                const float* __restrict__ b1, const float* __restrict__ Wh,
                const float* __restrict__ bh, const float* __restrict__ Wo,
                const float* __restrict__ bo, float* __restrict__ out,
                int n_iters)
{
    // swizzled: row R, 16B-slot kg stored at slot kg ^ (R&7)
    __shared__ __align__(16) short sW1[8 * 16 * 64];       // 16 KB, 8 tiles
    __shared__ __align__(16) short sWh[2 * 8 * 16 * 128];  // 64 KB, 2 layers

    const int tid   = threadIdx.x;
    const int o     = blockIdx.x >> 4;    // subnet
    const int slice = blockIdx.x & 15;    // row-slice

    char* const cW1 = (char*)sW1;
    char* const cWh = (char*)sWh;

    // ---------------- one-time staging (bf16, permuted, swizzled) ----------------
    {   // W1: exactly 1024 tasks (T,R,kg)
        const int R = tid & 15, T = (tid >> 4) & 7, kg = tid >> 7;    // kg:0..7
        const int c = 32 * (T >> 1) + 8 * (R >> 2) + 4 * (T & 1) + (R & 3);
        const float* p = W1 + ((size_t)o * IN_DIM + kg * 8) * HID + c;
        union { v8s v; unsigned u[4]; } cv;
        #pragma unroll
        for (int j = 0; j < 4; ++j)
            cv.u[j] = pk2(p[(2 * j) * HID], p[(2 * j + 1) * HID]);
        *(v8s*)(cW1 + T * 2048 + R * 128 + ((kg * 16) ^ ((R & 7) << 4))) = cv.v;
    }
    #pragma unroll
    for (int r = 0; r < 4; ++r) {          // Wh: 4096 tasks (l,T,R,kg)
        const int t = tid + r * 1024;
        const int R = t & 15, T = (t >> 4) & 7, kg = (t >> 7) & 15, l = t >> 11;
        const int c = 32 * (T >> 1) + 8 * (R >> 2) + 4 * (T & 1) + (R & 3);
        const float* p = Wh + (((size_t)l * OUT_DIM + o) * HID + kg * 8) * HID + c;
        union { v8s v; unsigned u[4]; } cv;
        #pragma unroll
        for (int j = 0; j < 4; ++j)
            cv.u[j] = pk2(p[(2 * j) * HID], p[(2 * j + 1) * HID]);
        *(v8s*)(cWh + l * 32768 + T * 4096 + R * 256 + ((kg * 16) ^ ((R & 7) << 4))) = cv.v;
    }
    __syncthreads();   // the ONLY block-wide barrier

    const int lane = tid & 63;
    const int w    = tid >> 6;    // wave id 0..15: owns rows [w*16, w*16+16)
    const int n    = lane & 15;   // fragment row/col index
    const int q    = lane >> 4;   // quad
    const float bo_v = bo[o];

    // loop-invariant swizzled k-slot byte offsets
    int kW1[2], kWh[4];
    #pragma unroll
    for (int kc = 0; kc < 2; ++kc) kW1[kc] = ((4 * kc + q) ^ (n & 7)) << 4;
    #pragma unroll
    for (int kc = 0; kc < 4; ++kc) kWh[kc] = ((4 * kc + q) ^ (n & 7)) << 4;

    const int w1base = n * 128;
    const int whbase = n * 256;

    // uniform global bases (SGPR) for bias/head; per-lane part is 8q (+z voffset)
    const char* const gB1 = (const char*)(b1 + o * HID + 8 * q);
    const char* const gH0 = (const char*)(bh + o * HID + 8 * q);
    const char* const gH1 = (const char*)(bh + (OUT_DIM + o) * HID + 8 * q);
    const char* const gWo = (const char*)(Wo + o * HID + 8 * q);

    for (int it = 0; it < n_iters; ++it) {
        // opaque zero, re-laundered each iteration: defeats LICM on LDS and
        // bias loads (keeps them in-loop instead of hoisted->spilled; R4 lesson)
        unsigned z = 0;
        asm volatile("" : "+v"(z));
        const char* const W1p = cW1 + w1base + z;   // + imm T*2048 + kW1[kc]
        const char* const Whp = cWh + whbase + z;   // + imm l*32768 + T*4096 + kWh[kc]
        const char* const B1p = gB1 + z;            // + imm 128*(T>>1)+16*(T&1)
        const char* const H0p = gH0 + z;
        const char* const H1p = gH1 + z;
        const char* const Wop = gWo + z;

        const int rowA = (slice * n_iters + it) * 512 + w * 16 + n;
        const int rowB = rowA + 256;

        // ---- x fragments for both tiles (B-operand, row-major, k-contiguous) ----
        v8s xbA[2], xbB[2];
        #pragma unroll
        for (int kc = 0; kc < 2; ++kc) {
            const float* xp = x + (size_t)rowA * IN_DIM + kc * 32 + q * 8;
            float4 f0 = *(const float4*)xp;
            float4 f1 = *(const float4*)(xp + 4);
            union { v8s v; unsigned u[4]; } cv;
            cv.u[0] = pk2(f0.x, f0.y); cv.u[1] = pk2(f0.z, f0.w);
            cv.u[2] = pk2(f1.x, f1.y); cv.u[3] = pk2(f1.z, f1.w);
            xbA[kc] = cv.v;
            const float* yp = x + (size_t)rowB * IN_DIM + kc * 32 + q * 8;
            float4 g0 = *(const float4*)yp;
            float4 g1 = *(const float4*)(yp + 4);
            cv.u[0] = pk2(g0.x, g0.y); cv.u[1] = pk2(g0.z, g0.w);
            cv.u[2] = pk2(g1.x, g1.y); cv.u[3] = pk2(g1.z, g1.w);
            xbB[kc] = cv.v;
        }

        // ================= layer 1: C^T = W1^T @ X^T =================
        v4f accA[8], accB[8];
        #pragma unroll
        for (int T = 0; T < 8; ++T) {    // one bias load inits BOTH tiles' acc
            v4f b = *(const v4f*)(B1p + 128 * (T >> 1) + 16 * (T & 1));
            accA[T] = b; accB[T] = b;
        }
        #pragma unroll
        for (int kc = 0; kc < 2; ++kc)
            #pragma unroll
            for (int T = 0; T < 8; ++T) {
                v8s a = *(const v8s*)(W1p + T * 2048 + kW1[kc]);   // shared A-frag
                accA[T] = __builtin_amdgcn_mfma_f32_16x16x32_bf16(a, xbA[kc], accA[T], 0, 0, 0);
                accB[T] = __builtin_amdgcn_mfma_f32_16x16x32_bf16(a, xbB[kc], accB[T], 0, 0, 0);
            }
        // packed H in next-layer B-operand order -- register-local handoff
        unsigned hA[16], hB[16];
        #pragma unroll
        for (int T = 0; T < 8; ++T) {
            const int i0 = (T >> 1) * 4 + 2 * (T & 1);
            hA[i0]     = pk2(swishf(accA[T][0]), swishf(accA[T][1]));
            hA[i0 + 1] = pk2(swishf(accA[T][2]), swishf(accA[T][3]));
            hB[i0]     = pk2(swishf(accB[T][0]), swishf(accB[T][1]));
            hB[i0 + 1] = pk2(swishf(accB[T][2]), swishf(accB[T][3]));
        }

        // ================= hidden layers =================
        #pragma unroll
        for (int l = 0; l < 2; ++l) {
            const char* const Bp = l ? H1p : H0p;
            #pragma unroll
            for (int T = 0; T < 8; ++T) {
                v4f b = *(const v4f*)(Bp + 128 * (T >> 1) + 16 * (T & 1));
                accA[T] = b; accB[T] = b;
            }
            #pragma unroll
            for (int kc = 0; kc < 4; ++kc) {
                v4u ta = { hA[kc * 4 + 0], hA[kc * 4 + 1], hA[kc * 4 + 2], hA[kc * 4 + 3] };
                v4u tb = { hB[kc * 4 + 0], hB[kc * 4 + 1], hB[kc * 4 + 2], hB[kc * 4 + 3] };
                v8s hvA = __builtin_bit_cast(v8s, ta);
                v8s hvB = __builtin_bit_cast(v8s, tb);
                #pragma unroll
                for (int T = 0; T < 8; ++T) {
                    v8s a = *(const v8s*)(Whp + l * 32768 + T * 4096 + kWh[kc]);
                    accA[T] = __builtin_amdgcn_mfma_f32_16x16x32_bf16(a, hvA, accA[T], 0, 0, 0);
                    accB[T] = __builtin_amdgcn_mfma_f32_16x16x32_bf16(a, hvB, accB[T], 0, 0, 0);
                }
            }
            if (l == 0) {
                #pragma unroll
                for (int T = 0; T < 8; ++T) {
                    const int i0 = (T >> 1) * 4 + 2 * (T & 1);
                    hA[i0]     = pk2(swishf(accA[T][0]), swishf(accA[T][1]));
                    hA[i0 + 1] = pk2(swishf(accA[T][2]), swishf(accA[T][3]));
                    hB[i0]     = pk2(swishf(accB[T][0]), swishf(accB[T][1]));
                    hB[i0 + 1] = pk2(swishf(accB[T][2]), swishf(accB[T][3]));
                }
            } else {
                // head fused into the epilogue (wo via L1-resident v4f loads)
                float pA = 0.0f, pB = 0.0f;
                #pragma unroll
                for (int T = 0; T < 8; ++T) {
                    v4f wo = *(const v4f*)(Wop + 128 * (T >> 1) + 16 * (T & 1));
                    pA += swishf(accA[T][0]) * wo[0];
                    pA += swishf(accA[T][1]) * wo[1];
                    pA += swishf(accA[T][2]) * wo[2];
                    pA += swishf(accA[T][3]) * wo[3];
                    pB += swishf(accB[T][0]) * wo[0];
                    pB += swishf(accB[T][1]) * wo[1];
                    pB += swishf(accB[T][2]) * wo[2];
                    pB += swishf(accB[T][3]) * wo[3];
                }
                pA += __shfl_xor(pA, 16);        // reduce across the 4 quads
                pA += __shfl_xor(pA, 32);
                pB += __shfl_xor(pB, 16);
                pB += __shfl_xor(pB, 32);
                if (lane < 16) {
                    out[(size_t)rowA * OUT_DIM + o] = pA + bo_v;
                    out[(size_t)rowB * OUT_DIM + o] = pB + bo_v;
                }
            }
        }
    }
}

extern "C" void kernel_launch(void* const* d_in, const int* in_sizes, int n_in,
                              void* d_out, int out_size, void* d_ws, size_t ws_size,
                              hipStream_t stream) {
    const float* x  = (const float*)d_in[0];
    const float* W1 = (const float*)d_in[1];
    const float* b1 = (const float*)d_in[2];
    const float* Wh = (const float*)d_in[3];
    const float* bh = (const float*)d_in[4];
    const float* Wo = (const float*)d_in[5];
    const float* bo = (const float*)d_in[6];
    float* out = (float*)d_out;

    const int N       = in_sizes[0] / IN_DIM;  // 32768
    const int n_iters = N / (16 * 512);        // 4: 16 slices x 512 rows/iter

    dim3 grid(OUT_DIM * 16);                   // 512 blocks: 32 subnets x 16 slices
    dim3 block(1024);                          // 16 waves, 80KB LDS
    subnet_mlp<<<grid, block, 0, stream>>>(x, W1, b1, Wh, bh, Wo, bo, out, n_iters);
}

// Round 10
// 232.860 us; speedup vs baseline: 1.3034x; 1.2754x over previous
//
#include <hip/hip_runtime.h>
#include <hip/hip_bf16.h>

#define IN_DIM  64
#define HID     128
#define OUT_DIM 32

typedef short    v8s __attribute__((ext_vector_type(8)));
typedef float    v4f __attribute__((ext_vector_type(4)));
typedef unsigned v4u __attribute__((ext_vector_type(4)));

__device__ __forceinline__ unsigned pk2(float a, float b) {
    __hip_bfloat162 p = __float22bfloat162_rn(make_float2(a, b));
    return *(unsigned*)&p;
}

// Grouped-reciprocal swish: 4 swish with ONE v_rcp (5 trans vs 8).
// exp arg clamped at 20 so the 4-way product (<= (1+e^20)^4 ~ 5e34) cannot
// overflow fp32; swish error from the clamp is < 1e-7 absolute.
__device__ __forceinline__ v4f swish4(v4f v) {
    float e0 = __expf(fminf(-v[0], 20.0f));
    float e1 = __expf(fminf(-v[1], 20.0f));
    float e2 = __expf(fminf(-v[2], 20.0f));
    float e3 = __expf(fminf(-v[3], 20.0f));
    float w0 = 1.0f + e0, w1 = 1.0f + e1, w2 = 1.0f + e2, w3 = 1.0f + e3;
    float w01 = w0 * w1, w23 = w2 * w3;
    float r   = __builtin_amdgcn_rcpf(w01 * w23);
    float r01 = r * w23, r23 = r * w01;          // 1/w01, 1/w23
    v4f s;
    s[0] = v[0] * (w1 * r01);                    // v0/w0
    s[1] = v[1] * (w0 * r01);
    s[2] = v[2] * (w3 * r23);
    s[3] = v[3] * (w2 * r23);
    return s;
}

// one-time x fp32 -> bf16 (row-major [N][64]); removes per-subnet re-conversion
__global__ __launch_bounds__(1024)
void cvt_x(const float* __restrict__ x, ushort* __restrict__ xb, int n8) {
    int i = blockIdx.x * blockDim.x + threadIdx.x;   // 8 floats per thread
    if (i < n8) {
        float4 f0 = *(const float4*)(x + (size_t)i * 8);
        float4 f1 = *(const float4*)(x + (size_t)i * 8 + 4);
        uint4 u;
        u.x = pk2(f0.x, f0.y); u.y = pk2(f0.z, f0.w);
        u.z = pk2(f1.x, f1.y); u.w = pk2(f1.z, f1.w);
        *(uint4*)(xb + (size_t)i * 8) = u;
    }
}

// Channel-permuted weight staging: tile T, row R holds physical channel
//   ch(T,R) = 32*(T>>1) + 8*(R>>2) + 4*(T&1) + (R&3)
// so each layer's MFMA C-output registers ARE the next layer's B-operand
// fragments (register-local handoff, zero main-loop barriers/slab).
// R5 base (best clean version, 268us): bias in LDS, single row-tile/wave,
// opaque-z launder on every LDS base (anti-LICM, the R4 spill lesson).
template<int BF16X>
__global__ __launch_bounds__(1024, 1)
void subnet_mlp(const float* __restrict__ x,  const ushort* __restrict__ xbf,
                const float* __restrict__ W1, const float* __restrict__ b1,
                const float* __restrict__ Wh, const float* __restrict__ bh,
                const float* __restrict__ Wo, const float* __restrict__ bo,
                float* __restrict__ out, int n_iters)
{
    // swizzled: row R, 16B-slot kg stored at slot kg ^ (R&7)
    __shared__ __align__(16) short sW1[8 * 16 * 64];       // 16 KB, 8 tiles
    __shared__ __align__(16) short sWh[2 * 8 * 16 * 128];  // 64 KB, 2 layers
    __shared__ __align__(16) float sBias[512];             // 2 KB: b1|bh0|bh1|wo

    const int tid   = threadIdx.x;
    const int o     = blockIdx.x >> 3;    // subnet
    const int slice = blockIdx.x & 7;     // row-slice

    char* const cW1 = (char*)sW1;
    char* const cWh = (char*)sWh;
    char* const cB  = (char*)sBias;

    // ---------------- one-time staging (bf16, permuted, swizzled) ----------------
    {   // W1: exactly 1024 tasks (T,R,kg)
        const int R = tid & 15, T = (tid >> 4) & 7, kg = tid >> 7;    // kg:0..7
        const int c = 32 * (T >> 1) + 8 * (R >> 2) + 4 * (T & 1) + (R & 3);
        const float* p = W1 + ((size_t)o * IN_DIM + kg * 8) * HID + c;
        union { v8s v; unsigned u[4]; } cv;
        #pragma unroll
        for (int j = 0; j < 4; ++j)
            cv.u[j] = pk2(p[(2 * j) * HID], p[(2 * j + 1) * HID]);
        *(v8s*)(cW1 + T * 2048 + R * 128 + ((kg * 16) ^ ((R & 7) << 4))) = cv.v;
    }
    #pragma unroll
    for (int r = 0; r < 4; ++r) {          // Wh: 4096 tasks (l,T,R,kg)
        const int t = tid + r * 1024;
        const int R = t & 15, T = (t >> 4) & 7, kg = (t >> 7) & 15, l = t >> 11;
        const int c = 32 * (T >> 1) + 8 * (R >> 2) + 4 * (T & 1) + (R & 3);
        const float* p = Wh + (((size_t)l * OUT_DIM + o) * HID + kg * 8) * HID + c;
        union { v8s v; unsigned u[4]; } cv;
        #pragma unroll
        for (int j = 0; j < 4; ++j)
            cv.u[j] = pk2(p[(2 * j) * HID], p[(2 * j + 1) * HID]);
        *(v8s*)(cWh + l * 32768 + T * 4096 + R * 256 + ((kg * 16) ^ ((R & 7) << 4))) = cv.v;
    }
    if (tid < 512) {                       // biases + head weights
        const int idx = tid & 127, seg = tid >> 7;
        float v;
        if      (seg == 0) v = b1[o * HID + idx];
        else if (seg == 1) v = bh[o * HID + idx];
        else if (seg == 2) v = bh[(OUT_DIM + o) * HID + idx];
        else               v = Wo[o * HID + idx];
        sBias[tid] = v;
    }
    __syncthreads();   // the ONLY block-wide barrier

    const int lane = tid & 63;
    const int w    = tid >> 6;    // wave id 0..15: owns rows [w*16, w*16+16)
    const int n    = lane & 15;   // fragment row/col index
    const int q    = lane >> 4;   // quad
    const float bo_v = bo[o];

    // loop-invariant swizzled k-slot byte offsets
    int kW1[2], kWh[4];
    #pragma unroll
    for (int kc = 0; kc < 2; ++kc) kW1[kc] = ((4 * kc + q) ^ (n & 7)) << 4;
    #pragma unroll
    for (int kc = 0; kc < 4; ++kc) kWh[kc] = ((4 * kc + q) ^ (n & 7)) << 4;

    const int w1base = n * 128;
    const int whbase = n * 256;
    const int bbase  = 32 * q;    // bias element 8q (byte)

    for (int it = 0; it < n_iters; ++it) {
        // opaque zero, re-laundered each iteration: defeats LICM on LDS loads
        unsigned z = 0;
        asm volatile("" : "+v"(z));
        const char* const W1p = cW1 + w1base + z;   // + imm T*2048 + kW1[kc]
        const char* const Whp = cWh + whbase + z;   // + imm l*32768 + T*4096 + kWh[kc]
        const char* const Bp  = cB  + bbase  + z;   // + imm seg*512 + 128*(T>>1)+16*(T&1)

        const int row = (slice * n_iters + it) * 256 + w * 16 + n;

        // ---- x fragments (B-operand, row-major, k-contiguous) ----
        v8s xb[2];
        if constexpr (BF16X) {
            const char* xr = (const char*)(xbf + (size_t)row * IN_DIM) + q * 16;
            xb[0] = *(const v8s*)(xr);
            xb[1] = *(const v8s*)(xr + 64);
        } else {
            #pragma unroll
            for (int kc = 0; kc < 2; ++kc) {
                const float* xp = x + (size_t)row * IN_DIM + kc * 32 + q * 8;
                float4 f0 = *(const float4*)xp;
                float4 f1 = *(const float4*)(xp + 4);
                union { v8s v; unsigned u[4]; } cv;
                cv.u[0] = pk2(f0.x, f0.y); cv.u[1] = pk2(f0.z, f0.w);
                cv.u[2] = pk2(f1.x, f1.y); cv.u[3] = pk2(f1.z, f1.w);
                xb[kc] = cv.v;
            }
        }

        // ================= layer 1: C^T = W1^T @ X^T =================
        v4f acc[8];
        #pragma unroll
        for (int T = 0; T < 8; ++T)      // bias rides the accumulator init (LDS broadcast)
            acc[T] = *(const v4f*)(Bp + 128 * (T >> 1) + 16 * (T & 1));
        #pragma unroll
        for (int kc = 0; kc < 2; ++kc)
            #pragma unroll
            for (int T = 0; T < 8; ++T) {
                v8s a = *(const v8s*)(W1p + T * 2048 + kW1[kc]);
                acc[T] = __builtin_amdgcn_mfma_f32_16x16x32_bf16(a, xb[kc], acc[T], 0, 0, 0);
            }
        // packed H, filled directly in next-layer B-operand order (k-slot s:
        // T=2kc+hi gives s=4*hi+j) -- register-local layer handoff
        unsigned h[16];
        #pragma unroll
        for (int T = 0; T < 8; ++T) {
            v4f s = swish4(acc[T]);
            const int i0 = (T >> 1) * 4 + 2 * (T & 1);
            h[i0]     = pk2(s[0], s[1]);
            h[i0 + 1] = pk2(s[2], s[3]);
        }

        // ================= hidden layers =================
        #pragma unroll
        for (int l = 0; l < 2; ++l) {
            #pragma unroll
            for (int T = 0; T < 8; ++T)
                acc[T] = *(const v4f*)(Bp + 512 + l * 512 + 128 * (T >> 1) + 16 * (T & 1));
            #pragma unroll
            for (int kc = 0; kc < 4; ++kc) {
                v4u tu = { h[kc * 4 + 0], h[kc * 4 + 1], h[kc * 4 + 2], h[kc * 4 + 3] };
                v8s hbv = __builtin_bit_cast(v8s, tu);
                #pragma unroll
                for (int T = 0; T < 8; ++T) {
                    v8s a = *(const v8s*)(Whp + l * 32768 + T * 4096 + kWh[kc]);
                    acc[T] = __builtin_amdgcn_mfma_f32_16x16x32_bf16(a, hbv, acc[T], 0, 0, 0);
                }
            }
            if (l == 0) {
                #pragma unroll
                for (int T = 0; T < 8; ++T) {
                    v4f s = swish4(acc[T]);
                    const int i0 = (T >> 1) * 4 + 2 * (T & 1);
                    h[i0]     = pk2(s[0], s[1]);
                    h[i0 + 1] = pk2(s[2], s[3]);
                }
            } else {
                // head fused into the epilogue (wo via LDS broadcast)
                float p = 0.0f;
                #pragma unroll
                for (int T = 0; T < 8; ++T) {
                    v4f wo = *(const v4f*)(Bp + 1536 + 128 * (T >> 1) + 16 * (T & 1));
                    v4f s  = swish4(acc[T]);
                    p += s[0] * wo[0];
                    p += s[1] * wo[1];
                    p += s[2] * wo[2];
                    p += s[3] * wo[3];
                }
                p += __shfl_xor(p, 16);          // reduce across the 4 quads
                p += __shfl_xor(p, 32);
                if (lane < 16)
                    out[(size_t)row * OUT_DIM + o] = p + bo_v;
            }
        }
    }
}

extern "C" void kernel_launch(void* const* d_in, const int* in_sizes, int n_in,
                              void* d_out, int out_size, void* d_ws, size_t ws_size,
                              hipStream_t stream) {
    const float* x  = (const float*)d_in[0];
    const float* W1 = (const float*)d_in[1];
    const float* b1 = (const float*)d_in[2];
    const float* Wh = (const float*)d_in[3];
    const float* bh = (const float*)d_in[4];
    const float* Wo = (const float*)d_in[5];
    const float* bo = (const float*)d_in[6];
    float* out = (float*)d_out;

    const int N       = in_sizes[0] / IN_DIM;  // 32768
    const int n_iters = N / (8 * 256);         // 16: 8 slices x 256 rows/iter

    dim3 grid(OUT_DIM * 8);                    // 256 blocks
    dim3 block(1024);                          // 16 waves share one weight copy

    const size_t need = (size_t)N * IN_DIM * sizeof(ushort);   // 4 MB
    if (d_ws != nullptr && ws_size >= need) {
        ushort* xbf = (ushort*)d_ws;
        const int n8 = N * IN_DIM / 8;         // 262144
        cvt_x<<<dim3((n8 + 1023) / 1024), dim3(1024), 0, stream>>>(x, xbf, n8);
        subnet_mlp<1><<<grid, block, 0, stream>>>(x, xbf, W1, b1, Wh, bh, Wo, bo, out, n_iters);
    } else {
        subnet_mlp<0><<<grid, block, 0, stream>>>(x, nullptr, W1, b1, Wh, bh, Wo, bo, out, n_iters);
    }
}

// Round 11
// 226.991 us; speedup vs baseline: 1.3371x; 1.0259x over previous
//
#include <hip/hip_runtime.h>
#include <hip/hip_bf16.h>
#include <cmath>
#include <algorithm>

#define IN_DIM  64
#define HID     128
#define OUT_DIM 32

typedef short    v8s __attribute__((ext_vector_type(8)));
typedef float    v4f __attribute__((ext_vector_type(4)));
typedef unsigned v4u __attribute__((ext_vector_type(4)));

struct SigP { float k1; float c[12]; };   // sigmoid(v) ~ 0.5 + u*P(s), s = k1*u^2 - 1

__device__ __forceinline__ unsigned pk2(float a, float b) {
    __hip_bfloat162 p = __float22bfloat162_rn(make_float2(a, b));
    return *(unsigned*)&p;
}

// ---- poly swish: 0 transcendentals, ~16 VALU/value ----
__device__ __forceinline__ float swish_p(float v, const SigP& P) {
    float u = fminf(fmaxf(v, -8.5f), 8.5f);     // v_med3
    float z = u * u;
    float s = fmaf(z, P.k1, -1.0f);
    float g = P.c[11];
    #pragma unroll
    for (int k = 10; k >= 0; --k) g = fmaf(g, s, P.c[k]);
    float sig = fmaf(u, g, 0.5f);
    return v * sig;
}
__device__ __forceinline__ v4f swish_p4(v4f v, const SigP& P) {
    v4f r;
    r[0] = swish_p(v[0], P); r[1] = swish_p(v[1], P);
    r[2] = swish_p(v[2], P); r[3] = swish_p(v[3], P);
    return r;
}

// ---- exact fallback: grouped-reciprocal swish (5 trans / 4 values) ----
__device__ __forceinline__ v4f swish4(v4f v) {
    float e0 = __expf(fminf(-v[0], 20.0f));
    float e1 = __expf(fminf(-v[1], 20.0f));
    float e2 = __expf(fminf(-v[2], 20.0f));
    float e3 = __expf(fminf(-v[3], 20.0f));
    float w0 = 1.0f + e0, w1 = 1.0f + e1, w2 = 1.0f + e2, w3 = 1.0f + e3;
    float w01 = w0 * w1, w23 = w2 * w3;
    float r   = __builtin_amdgcn_rcpf(w01 * w23);
    float r01 = r * w23, r23 = r * w01;
    v4f s;
    s[0] = v[0] * (w1 * r01);
    s[1] = v[1] * (w0 * r01);
    s[2] = v[2] * (w3 * r23);
    s[3] = v[3] * (w2 * r23);
    return s;
}

// one-time x fp32 -> bf16 (row-major [N][64])
__global__ __launch_bounds__(1024)
void cvt_x(const float* __restrict__ x, ushort* __restrict__ xb, int n8) {
    int i = blockIdx.x * blockDim.x + threadIdx.x;
    if (i < n8) {
        float4 f0 = *(const float4*)(x + (size_t)i * 8);
        float4 f1 = *(const float4*)(x + (size_t)i * 8 + 4);
        uint4 u;
        u.x = pk2(f0.x, f0.y); u.y = pk2(f0.z, f0.w);
        u.z = pk2(f1.x, f1.y); u.w = pk2(f1.z, f1.w);
        *(uint4*)(xb + (size_t)i * 8) = u;
    }
}

// Channel-permuted weight staging (register-local layer handoff), bias in LDS,
// opaque-z anti-LICM launder. R8 base structure (183us main kernel).
template<int BF16X, int POLY>
__global__ __launch_bounds__(1024, 1)
void subnet_mlp(const float* __restrict__ x,  const ushort* __restrict__ xbf,
                const float* __restrict__ W1, const float* __restrict__ b1,
                const float* __restrict__ Wh, const float* __restrict__ bh,
                const float* __restrict__ Wo, const float* __restrict__ bo,
                float* __restrict__ out, int n_iters, SigP SP)
{
    __shared__ __align__(16) short sW1[8 * 16 * 64];       // 16 KB
    __shared__ __align__(16) short sWh[2 * 8 * 16 * 128];  // 64 KB
    __shared__ __align__(16) float sBias[512];             // 2 KB

    const int tid   = threadIdx.x;
    const int o     = blockIdx.x >> 3;
    const int slice = blockIdx.x & 7;

    char* const cW1 = (char*)sW1;
    char* const cWh = (char*)sWh;
    char* const cB  = (char*)sBias;

    {   // W1 staging: 1024 tasks (T,R,kg)
        const int R = tid & 15, T = (tid >> 4) & 7, kg = tid >> 7;
        const int c = 32 * (T >> 1) + 8 * (R >> 2) + 4 * (T & 1) + (R & 3);
        const float* p = W1 + ((size_t)o * IN_DIM + kg * 8) * HID + c;
        union { v8s v; unsigned u[4]; } cv;
        #pragma unroll
        for (int j = 0; j < 4; ++j)
            cv.u[j] = pk2(p[(2 * j) * HID], p[(2 * j + 1) * HID]);
        *(v8s*)(cW1 + T * 2048 + R * 128 + ((kg * 16) ^ ((R & 7) << 4))) = cv.v;
    }
    #pragma unroll
    for (int r = 0; r < 4; ++r) {   // Wh staging: 4096 tasks
        const int t = tid + r * 1024;
        const int R = t & 15, T = (t >> 4) & 7, kg = (t >> 7) & 15, l = t >> 11;
        const int c = 32 * (T >> 1) + 8 * (R >> 2) + 4 * (T & 1) + (R & 3);
        const float* p = Wh + (((size_t)l * OUT_DIM + o) * HID + kg * 8) * HID + c;
        union { v8s v; unsigned u[4]; } cv;
        #pragma unroll
        for (int j = 0; j < 4; ++j)
            cv.u[j] = pk2(p[(2 * j) * HID], p[(2 * j + 1) * HID]);
        *(v8s*)(cWh + l * 32768 + T * 4096 + R * 256 + ((kg * 16) ^ ((R & 7) << 4))) = cv.v;
    }
    if (tid < 512) {
        const int idx = tid & 127, seg = tid >> 7;
        float v;
        if      (seg == 0) v = b1[o * HID + idx];
        else if (seg == 1) v = bh[o * HID + idx];
        else if (seg == 2) v = bh[(OUT_DIM + o) * HID + idx];
        else               v = Wo[o * HID + idx];
        sBias[tid] = v;
    }
    __syncthreads();   // the ONLY block-wide barrier

    const int lane = tid & 63;
    const int w    = tid >> 6;
    const int n    = lane & 15;
    const int q    = lane >> 4;
    const float bo_v = bo[o];

    int kW1[2], kWh[4];
    #pragma unroll
    for (int kc = 0; kc < 2; ++kc) kW1[kc] = ((4 * kc + q) ^ (n & 7)) << 4;
    #pragma unroll
    for (int kc = 0; kc < 4; ++kc) kWh[kc] = ((4 * kc + q) ^ (n & 7)) << 4;

    const int w1base = n * 128;
    const int whbase = n * 256;
    const int bbase  = 32 * q;

    for (int it = 0; it < n_iters; ++it) {
        unsigned z = 0;
        asm volatile("" : "+v"(z));        // anti-LICM launder (R4 lesson)
        const char* const W1p = cW1 + w1base + z;
        const char* const Whp = cWh + whbase + z;
        const char* const Bp  = cB  + bbase  + z;

        const int row = (slice * n_iters + it) * 256 + w * 16 + n;

        v8s xb[2];
        if constexpr (BF16X) {
            const char* xr = (const char*)(xbf + (size_t)row * IN_DIM) + q * 16;
            xb[0] = *(const v8s*)(xr);
            xb[1] = *(const v8s*)(xr + 64);
        } else {
            #pragma unroll
            for (int kc = 0; kc < 2; ++kc) {
                const float* xp = x + (size_t)row * IN_DIM + kc * 32 + q * 8;
                float4 f0 = *(const float4*)xp;
                float4 f1 = *(const float4*)(xp + 4);
                union { v8s v; unsigned u[4]; } cv;
                cv.u[0] = pk2(f0.x, f0.y); cv.u[1] = pk2(f0.z, f0.w);
                cv.u[2] = pk2(f1.x, f1.y); cv.u[3] = pk2(f1.z, f1.w);
                xb[kc] = cv.v;
            }
        }

        // ---------------- layer 1 ----------------
        v4f acc[8];
        #pragma unroll
        for (int T = 0; T < 8; ++T)
            acc[T] = *(const v4f*)(Bp + 128 * (T >> 1) + 16 * (T & 1));
        #pragma unroll
        for (int kc = 0; kc < 2; ++kc)
            #pragma unroll
            for (int T = 0; T < 8; ++T) {
                v8s a = *(const v8s*)(W1p + T * 2048 + kW1[kc]);
                acc[T] = __builtin_amdgcn_mfma_f32_16x16x32_bf16(a, xb[kc], acc[T], 0, 0, 0);
            }
        unsigned h[16];
        #pragma unroll
        for (int T = 0; T < 8; ++T) {
            v4f s = POLY ? swish_p4(acc[T], SP) : swish4(acc[T]);
            const int i0 = (T >> 1) * 4 + 2 * (T & 1);
            h[i0]     = pk2(s[0], s[1]);
            h[i0 + 1] = pk2(s[2], s[3]);
        }

        // ---------------- hidden layers ----------------
        #pragma unroll
        for (int l = 0; l < 2; ++l) {
            #pragma unroll
            for (int T = 0; T < 8; ++T)
                acc[T] = *(const v4f*)(Bp + 512 + l * 512 + 128 * (T >> 1) + 16 * (T & 1));
            #pragma unroll
            for (int kc = 0; kc < 4; ++kc) {
                v4u tu = { h[kc * 4 + 0], h[kc * 4 + 1], h[kc * 4 + 2], h[kc * 4 + 3] };
                v8s hbv = __builtin_bit_cast(v8s, tu);
                #pragma unroll
                for (int T = 0; T < 8; ++T) {
                    v8s a = *(const v8s*)(Whp + l * 32768 + T * 4096 + kWh[kc]);
                    acc[T] = __builtin_amdgcn_mfma_f32_16x16x32_bf16(a, hbv, acc[T], 0, 0, 0);
                }
            }
            if (l == 0) {
                #pragma unroll
                for (int T = 0; T < 8; ++T) {
                    v4f s = POLY ? swish_p4(acc[T], SP) : swish4(acc[T]);
                    const int i0 = (T >> 1) * 4 + 2 * (T & 1);
                    h[i0]     = pk2(s[0], s[1]);
                    h[i0 + 1] = pk2(s[2], s[3]);
                }
            } else {
                float p = 0.0f;
                #pragma unroll
                for (int T = 0; T < 8; ++T) {
                    v4f wo = *(const v4f*)(Bp + 1536 + 128 * (T >> 1) + 16 * (T & 1));
                    v4f s  = POLY ? swish_p4(acc[T], SP) : swish4(acc[T]);
                    p += s[0] * wo[0];
                    p += s[1] * wo[1];
                    p += s[2] * wo[2];
                    p += s[3] * wo[3];
                }
                p += __shfl_xor(p, 16);
                p += __shfl_xor(p, 32);
                if (lane < 16)
                    out[(size_t)row * OUT_DIM + o] = p + bo_v;
            }
        }
    }
}

// ---------------- host: fit sigmoid poly once, verify in float ----------------
struct SigFit { SigP p; bool ok; };

static SigFit make_fit() {
    SigFit F{}; F.ok = false;
    constexpr int NC = 12;
    const double CL = 8.5, zmax = CL * CL;
    const int NS = 4000;
    double A[NC][NC] = {}, rhs[NC] = {};
    for (int i = 0; i < NS; ++i) {
        double v = CL * (i + 0.5) / NS;
        double zz = v * v, s = 2.0 * zz / zmax - 1.0;
        double g = (1.0 / (1.0 + std::exp(-v)) - 0.5) / v;
        double T[NC]; T[0] = 1; T[1] = s;
        for (int k = 2; k < NC; ++k) T[k] = 2 * s * T[k - 1] - T[k - 2];
        double wt = 0.05 + zz; wt = wt * wt;   // ~z^2: swish err = v^2 * dg
        for (int r = 0; r < NC; ++r) {
            rhs[r] += wt * T[r] * g;
            for (int c = 0; c < NC; ++c) A[r][c] += wt * T[r] * T[c];
        }
    }
    double a[NC];
    {   // Gaussian elimination, partial pivot
        double M[NC][NC + 1];
        for (int r = 0; r < NC; ++r) { for (int c = 0; c < NC; ++c) M[r][c] = A[r][c]; M[r][NC] = rhs[r]; }
        for (int col = 0; col < NC; ++col) {
            int piv = col;
            for (int r = col + 1; r < NC; ++r)
                if (std::fabs(M[r][col]) > std::fabs(M[piv][col])) piv = r;
            for (int c = col; c <= NC; ++c) std::swap(M[piv][c], M[col][c]);
            if (std::fabs(M[col][col]) < 1e-280) return F;
            for (int r = col + 1; r < NC; ++r) {
                double f = M[r][col] / M[col][col];
                for (int c = col; c <= NC; ++c) M[r][c] -= f * M[col][c];
            }
        }
        for (int r = NC - 1; r >= 0; --r) {
            double acc2 = M[r][NC];
            for (int c = r + 1; c < NC; ++c) acc2 -= M[r][c] * a[c];
            a[r] = acc2 / M[r][r];
        }
    }
    // Chebyshev -> monomial in s
    double mono[NC] = {}, tp[NC] = {}, tc[NC] = {}, tn[NC];
    tp[0] = 1;
    for (int j = 0; j < NC; ++j) mono[j] += a[0] * tp[j];
    tc[1] = 1;
    for (int j = 0; j < NC; ++j) mono[j] += a[1] * tc[j];
    for (int k = 2; k < NC; ++k) {
        tn[0] = -tp[0];
        for (int j = 1; j < NC; ++j) tn[j] = 2 * tc[j - 1] - tp[j];
        for (int j = 0; j < NC; ++j) mono[j] += a[k] * tn[j];
        for (int j = 0; j < NC; ++j) { tp[j] = tc[j]; tc[j] = tn[j]; }
    }
    F.p.k1 = (float)(2.0 / zmax);
    for (int j = 0; j < NC; ++j) F.p.c[j] = (float)mono[j];
    // float verification with kernel-identical arithmetic
    double maxerr = 0;
    for (int i = 0; i <= 4000; ++i) {
        float v = -10.f + 20.f * (float)i / 4000.f;
        float u = fminf(fmaxf(v, -8.5f), 8.5f);
        float zz = u * u;
        float s = fmaf(zz, F.p.k1, -1.0f);
        float g = F.p.c[11];
        for (int k = 10; k >= 0; --k) g = fmaf(g, s, F.p.c[k]);
        float sig = fmaf(u, g, 0.5f);
        float sw = v * sig;
        double swt = (double)v / (1.0 + std::exp(-(double)v));
        maxerr = std::max(maxerr, std::fabs((double)sw - swt));
    }
    F.ok = (maxerr < 1.5e-3);
    return F;
}

extern "C" void kernel_launch(void* const* d_in, const int* in_sizes, int n_in,
                              void* d_out, int out_size, void* d_ws, size_t ws_size,
                              hipStream_t stream) {
    const float* x  = (const float*)d_in[0];
    const float* W1 = (const float*)d_in[1];
    const float* b1 = (const float*)d_in[2];
    const float* Wh = (const float*)d_in[3];
    const float* bh = (const float*)d_in[4];
    const float* Wo = (const float*)d_in[5];
    const float* bo = (const float*)d_in[6];
    float* out = (float*)d_out;

    const int N       = in_sizes[0] / IN_DIM;  // 32768
    const int n_iters = N / (8 * 256);         // 16

    dim3 grid(OUT_DIM * 8);                    // 256 blocks = 1/CU
    dim3 block(1024);

    static const SigFit SF = make_fit();       // host fit, once

    const size_t need = (size_t)N * IN_DIM * sizeof(ushort);   // 4 MB
    const bool bf = (d_ws != nullptr && ws_size >= need);
    if (bf) {
        ushort* xbf = (ushort*)d_ws;
        const int n8 = N * IN_DIM / 8;
        cvt_x<<<dim3((n8 + 1023) / 1024), dim3(1024), 0, stream>>>(x, xbf, n8);
        if (SF.ok) subnet_mlp<1, 1><<<grid, block, 0, stream>>>(x, xbf, W1, b1, Wh, bh, Wo, bo, out, n_iters, SF.p);
        else       subnet_mlp<1, 0><<<grid, block, 0, stream>>>(x, xbf, W1, b1, Wh, bh, Wo, bo, out, n_iters, SF.p);
    } else {
        if (SF.ok) subnet_mlp<0, 1><<<grid, block, 0, stream>>>(x, nullptr, W1, b1, Wh, bh, Wo, bo, out, n_iters, SF.p);
        else       subnet_mlp<0, 0><<<grid, block, 0, stream>>>(x, nullptr, W1, b1, Wh, bh, Wo, bo, out, n_iters, SF.p);
    }
}